// Round 6
// baseline (75.941 us; speedup 1.0000x reference)
//
#include <hip/hip_runtime.h>
#include <stdint.h>

#define HH 96
#define WW 96
#define NN (HH*WW)
#define NW 192   // bitmap words: 96 rows x 2 (128-bit padded rows, cols 96..127 dead)
#define NMT 24   // m-tiles for rank partials
#define MT 384   // m-tile size (NMT*MT == NN)
#define NKT 3    // k-tiles of 3072 (3 keys/thread)
#define KW_OFF 442368   // 9216*24*2 bytes of u16 partials

// ws layout (bytes):
//   [0, 442368)         rank16 u16[9216][24]  exact stable-rank partials,
//                       TRANSPOSED so each cell's 24 partials are 48
//                       contiguous bytes (3x uint4 loads in kout)
//   [442368, 443904)    kw     u64[192]       kept bitmap words
// R4 lesson (measured): cross-block sync via agent-scope atomics costs ~80us
// of L2-invalidate/writeback storms on multi-XCD gfx950 -> kA hit 88us.
// Two dispatches with zero cross-block sync is the right structure (R6/R8).

__device__ __forceinline__ int coord1(int a) { return (10 * a + 1) / 3; }

// Compile-time-specialized shifted word for half H, col shift DJ.
// 128-bit row = (A low cols 0..63, B high cols 64..127); S = own-half word,
// O = other-half word. Result bit b (cell col 64H+b) = row bit (64H+b+DJ).
template<int H, int DJ>
__device__ __forceinline__ unsigned long long shf(unsigned long long S,
                                                  unsigned long long O) {
    if constexpr (DJ == 0) {
        return S;
    } else if constexpr (H == 0) {
        if constexpr (DJ > 0) return (S >> DJ) | (O << (64 - DJ));  // B feeds high bits
        else                  return (S << (-DJ));                  // left of A is 0
    } else {
        if constexpr (DJ > 0) return (S >> DJ);                     // right of B is 0
        else                  return (S << (-DJ)) | (O >> (64 + DJ)); // A feeds low bits
    }
}

// Column-geometry masks: bit b set iff cm3(col 64H+b) == 1 (C1) / == 2 (C2).
template<int H> struct CM;
template<> struct CM<0> {
    static constexpr unsigned long long C1 = 0x2492492492492492ULL;  // b%3==1
    static constexpr unsigned long long C2 = 0x4924924924924924ULL;  // b%3==2
};
template<> struct CM<1> {
    static constexpr unsigned long long C1 = 0x9249249249249249ULL;  // (b+64)%3==1
    static constexpr unsigned long long C2 = 0x2492492492492492ULL;  // (b+64)%3==2
};

// Free-running monotone fixpoint (R10 protocol preserved): one thread per
// word, h compile-time per wave. Write K-then-D, read D-then-K, volatile:
// D=1 observed => that word's K is current. Own word lives in registers.
// Derived H edges: H[+e] = ~shifted(H[-e]) & geo-mask (exact under the
// tiebreak sign convention); spurious complement bits only hit dead cells /
// padding cols (D=1,K=0 from init -> harmless), col-0 dj=-1 masked.
// Inner 3x relaxation: horizontal edges re-applied with fresh own word
// (monotone-safe with the stale-but-ordered neighbor snapshot).
template<int H>
__device__ __forceinline__ unsigned long long runfix(
    const int row, const unsigned long long* Hc,
    volatile unsigned long long* vKs, volatile unsigned long long* vKo,
    volatile unsigned long long* vDs, volatile unsigned long long* vDo,
    unsigned long long myK, unsigned long long myD) {
    const int w  = row * 2 + H;
    const int wo = row * 2 + (H ^ 1);
    const bool okm1 = row >= 1, okp1 = row <= HH - 2;
    const bool okm2 = row >= 2, okp2 = row <= HH - 3;
    const int rm3 = row % 3;
    unsigned long long Hr[12];
    {
        const unsigned long long h0s = Hc[0*NW+w], h0o = Hc[0*NW+wo];
        const unsigned long long h2s = Hc[1*NW+w], h2o = Hc[1*NW+wo];
        Hr[0] = h0s;                                  // (0,-1) computed
        Hr[1] = ~shf<H,1>(h0s, h0o);                  // (0,+1) derived
        Hr[2] = h2s;                                  // (0,-2) computed
        Hr[3] = (~shf<H,2>(h2s, h2o)) & CM<H>::C2;    // (0,+2) derived, geo cm3==2
        Hr[4] = Hc[2*NW+w];                           // (-1,0) computed
        Hr[6] = Hc[3*NW+w];                           // (-2,0) computed
        Hr[8] = Hc[4*NW+w];                           // (-1,-1) computed
        Hr[9] = Hc[5*NW+w];                           // (-1,+1) computed
        Hr[5] = okp1 ? ~Hc[2*NW+w+2] : 0ULL;          // (+1,0) derived
        Hr[7] = (okp2 && rm3 == 2) ? ~Hc[3*NW+w+4] : 0ULL;  // (+2,0) derived
        if (okp1) {
            const unsigned long long a8 = Hc[4*NW+w+2], b8 = Hc[4*NW+wo+2];
            unsigned long long t11 = ~shf<H,1>(a8, b8);    // (+1,+1) from (-1,-1)@r+1
            const unsigned long long a9 = Hc[5*NW+w+2], b9 = Hc[5*NW+wo+2];
            unsigned long long t10 = ~shf<H,-1>(a9, b9);   // (+1,-1) from (-1,+1)@r+1
            if (rm3 == 1) { t11 &= ~CM<H>::C1; t10 &= ~CM<H>::C2; }
            if constexpr (H == 0) t10 &= ~1ULL;            // col 0 has no col -1
            Hr[11] = t11; Hr[10] = t10;
        } else { Hr[11] = 0ULL; Hr[10] = 0ULL; }
    }
    for (int iter = 0; iter < 4096; ++iter) {
        if (!~myD) break;                          // fully determined: final
        // ---- D reads FIRST (out-of-grid rows: H=0 there anyway) ----
        const unsigned long long D0o  = vDo[row];
        const unsigned long long Dm1s = okm1 ? vDs[row-1] : 0ULL;
        const unsigned long long Dm1o = okm1 ? vDo[row-1] : 0ULL;
        const unsigned long long Dp1s = okp1 ? vDs[row+1] : 0ULL;
        const unsigned long long Dp1o = okp1 ? vDo[row+1] : 0ULL;
        const unsigned long long Dm2  = okm2 ? vDs[row-2] : 0ULL;
        const unsigned long long Dp2  = okp2 ? vDs[row+2] : 0ULL;
        // ---- K reads AFTER D ----
        const unsigned long long K0o  = vKo[row];
        const unsigned long long Km1s = okm1 ? vKs[row-1] : 0ULL;
        const unsigned long long Km1o = okm1 ? vKo[row-1] : 0ULL;
        const unsigned long long Kp1s = okp1 ? vKs[row+1] : 0ULL;
        const unsigned long long Kp1o = okp1 ? vKo[row+1] : 0ULL;
        const unsigned long long Km2  = okm2 ? vKs[row-2] : 0ULL;
        const unsigned long long Kp2  = okp2 ? vKs[row+2] : 0ULL;

        const unsigned long long suppV =
              (Hr[4]  & Km1s) | (Hr[5] & Kp1s) | (Hr[6] & Km2) | (Hr[7] & Kp2)
            | (Hr[8]  & shf<H,-1>(Km1s, Km1o)) | (Hr[9]  & shf<H,1>(Km1s, Km1o))
            | (Hr[10] & shf<H,-1>(Kp1s, Kp1o)) | (Hr[11] & shf<H,1>(Kp1s, Kp1o));
        unsigned long long alldetV = ~0ULL;
        alldetV &= ~Hr[4]  | Dm1s;
        alldetV &= ~Hr[5]  | Dp1s;
        alldetV &= ~Hr[6]  | Dm2;
        alldetV &= ~Hr[7]  | Dp2;
        alldetV &= ~Hr[8]  | shf<H,-1>(Dm1s, Dm1o);
        alldetV &= ~Hr[9]  | shf<H,1>(Dm1s, Dm1o);
        alldetV &= ~Hr[10] | shf<H,-1>(Dp1s, Dp1o);
        alldetV &= ~Hr[11] | shf<H,1>(Dp1s, Dp1o);

        #pragma unroll
        for (int in = 0; in < 3; ++in) {           // horizontal in-register relax
            const unsigned long long supp = suppV
                | (Hr[0] & shf<H,-1>(myK, K0o)) | (Hr[1] & shf<H,1>(myK, K0o))
                | (Hr[2] & shf<H,-2>(myK, K0o)) | (Hr[3] & shf<H,2>(myK, K0o));
            const unsigned long long alldet = alldetV
                & (~Hr[0] | shf<H,-1>(myD, D0o)) & (~Hr[1] | shf<H,1>(myD, D0o))
                & (~Hr[2] | shf<H,-2>(myD, D0o)) & (~Hr[3] | shf<H,2>(myD, D0o));
            const unsigned long long U = ~myD;
            myK |= U & alldet & ~supp;
            myD |= U & (supp | alldet);
        }
        vKs[row] = myK;                            // K write BEFORE D write
        vDs[row] = myD;
    }
    return myK;
}

// One dispatch, disjoint block roles, ZERO cross-block sync (R6/R8 + R4).
// Block 0: bit-parallel greedy NMS. Blocks 1..72: exact stable-rank
// partials via u64 packed keys, 3 k-keys/thread x 384-m-tile (1152 compares
// per thread, ~1us -- still under the NMS block, so kA = max() unchanged).
//   key = (score_bits<<14) | (16383-idx):  key_m > key_k  <=>
//   (b_m > b_k) || (b_m==b_k && m<k)  -- single 64-bit compare per element.
// Partials stored TRANSPOSED as u16[cell][24] (counts <= 384 < 2^16, exact)
// so kout reads 48 contiguous bytes per cell.
__global__ __launch_bounds__(1024, 1) void kA(const float* __restrict__ cls,
                                              unsigned short* __restrict__ rank16,
                                              unsigned long long* __restrict__ kw) {
    __shared__ __align__(16) float s[NN];         // 36 KB (rank blocks alias 3 KB)
    __shared__ unsigned long long Hc[6][NW];      // 9 KB (computed-edge masks)
    __shared__ unsigned long long K2[2][HH], D2[2][HH];   // [h][row], 3 KB
    const int tid = threadIdx.x;
    const int bid = blockIdx.x;

    if (bid != 0) {
        // ---- rank partials: (k-tile of 3072, 3 keys/thread) x (m-tile of 384) ----
        const int rb = bid - 1;
        const int kt = rb % NKT, mt = rb / NKT;
        const int base = mt * MT;
        unsigned long long* sk = (unsigned long long*)s;
        if (tid < MT) {
            const int m = base + tid;
            sk[tid] = ((unsigned long long)__float_as_uint(cls[m]) << 14)
                    | (unsigned long long)(16383 - m);
        }
        __syncthreads();
        const int k0 = kt * 3072 + tid;
        const unsigned long long kk0 =
            ((unsigned long long)__float_as_uint(cls[k0]) << 14)
          | (unsigned long long)(16383 - k0);
        const unsigned long long kk1 =
            ((unsigned long long)__float_as_uint(cls[k0 + 1024]) << 14)
          | (unsigned long long)(16383 - (k0 + 1024));
        const unsigned long long kk2 =
            ((unsigned long long)__float_as_uint(cls[k0 + 2048]) << 14)
          | (unsigned long long)(16383 - (k0 + 2048));
        const ulonglong2* sk2 = (const ulonglong2*)sk;
        unsigned a0 = 0, a1 = 0, a2 = 0;
        #pragma unroll 8
        for (int m2 = 0; m2 < MT / 2; ++m2) {
            const ulonglong2 v = sk2[m2];   // broadcast read, conflict-free
            a0 += (v.x > kk0) + (v.y > kk0);
            a1 += (v.x > kk1) + (v.y > kk1);
            a2 += (v.x > kk2) + (v.y > kk2);
        }
        unsigned short* rp = rank16 + (size_t)k0 * NMT + mt;
        rp[0]                       = (unsigned short)a0;
        rp[(size_t)1024 * NMT]      = (unsigned short)a1;
        rp[(size_t)2048 * NMT]      = (unsigned short)a2;
        return;
    }

    // ---- NMS block (bid == 0) ----
    const int lane = tid & 63;
    const int wave = __builtin_amdgcn_readfirstlane(tid >> 6);  // force SALU
    for (int i = tid; i < NN/4; i += 1024)
        ((float4*)s)[i] = ((const float4*)cls)[i];
    __syncthreads();
    // Build 6 computed H masks (all tb: >=) + K/D init via ballot. Geometry
    // and bounds are folded into per-word CONSTANT masks applied to the
    // ballot result (scalar ops; wave/row/h forced wave-uniform), so the
    // per-lane work is just clamp+read+compare. Clamped OOB neighbor reads
    // stay inside s[] (garbage value, masked out). Mask content verified
    // edge-by-edge identical to the predicate form (col>=2 for (0,-2) via
    // ~3; col<=94 for (-1,+1) via bit31; dead cols via I; rows via 0-word).
    for (int it = 0; it < 12; ++it) {
        const int w = wave + (it << 4);
        const int row = w >> 1;
        const int h = w & 1;
        const int col = (h << 6) + lane;
        const int c = row * WW + col;
        const int cc = c < NN ? c : NN - 1;
        const unsigned bc = __float_as_uint(s[cc]);
        const int rm3 = row % 3;
        const unsigned long long I  = h ? 0x00000000FFFFFFFFULL : ~0ULL;
        const unsigned long long C1 = h ? 0x9249249249249249ULL : 0x2492492492492492ULL;
        const unsigned long long C2 = h ? 0x2492492492492492ULL : 0x4924924924924924ULL;
        const unsigned long long dinit = __ballot(!(__uint_as_float(bc) > 0.6f)) | ~I;
        if (lane == 0) { D2[h][row] = dinit; K2[h][row] = 0ULL; }
        auto nb = [&](int off) -> unsigned long long {
            int v = c + off;
            v = v < 0 ? 0 : (v >= NN ? NN - 1 : v);
            return __ballot(__float_as_uint(s[v]) >= bc);
        };
        const unsigned long long b0 = nb(-1);        // (0,-1)
        const unsigned long long b1 = nb(-2);        // (0,-2)
        const unsigned long long b2 = nb(-WW);       // (-1,0)
        const unsigned long long b3 = nb(-2*WW);     // (-2,0)
        const unsigned long long b4 = nb(-WW-1);     // (-1,-1)
        const unsigned long long b5 = nb(-WW+1);     // (-1,+1)
        if (lane == 0) {
            Hc[0][w] = b0 & I & (h ? ~0ULL : ~1ULL);
            Hc[1][w] = b1 & I & C1 & (h ? ~0ULL : ~3ULL);
            Hc[2][w] = (row >= 1) ? (b2 & I) : 0ULL;
            Hc[3][w] = (row >= 2 && rm3 == 1) ? (b3 & I) : 0ULL;
            Hc[4][w] = (row >= 1)
                ? (b4 & I & (rm3 == 2 ? ~C2 : ~0ULL) & (h ? ~0ULL : ~1ULL)) : 0ULL;
            Hc[5][w] = (row >= 1)
                ? (b5 & I & (rm3 == 2 ? ~C1 : ~0ULL)
                      & (h ? 0xFFFFFFFF7FFFFFFFULL : ~0ULL)) : 0ULL;
        }
    }
    __syncthreads();          // last barrier: all 16 waves present
    // Fixpoint threads: 4 waves x 48 lanes; h = wave>>1 is WAVE-UNIFORM so
    // the loop is compile-time specialized by half (no runtime h selects).
    if (wave >= 4 || lane >= 48) return;
    const int h2 = wave >> 1;
    const int row = ((wave & 1) * 48) + lane;
    const unsigned long long myK = K2[h2][row], myD = D2[h2][row];
    unsigned long long fin;
    if (h2 == 0)
        fin = runfix<0>(row, &Hc[0][0],
                        (volatile unsigned long long*)&K2[0][0],
                        (volatile unsigned long long*)&K2[1][0],
                        (volatile unsigned long long*)&D2[0][0],
                        (volatile unsigned long long*)&D2[1][0], myK, myD);
    else
        fin = runfix<1>(row, &Hc[0][0],
                        (volatile unsigned long long*)&K2[1][0],
                        (volatile unsigned long long*)&K2[0][0],
                        (volatile unsigned long long*)&D2[1][0],
                        (volatile unsigned long long*)&D2[0][0], myK, myD);
    kw[row * 2 + h2] = fin;   // own word final; no cross-wave read needed
}

// Epilogue: r = rank[k] is a permutation of [0,9216) — every output row
// written exactly once (non-kept rows -> zeros, no d_out memset needed).
// Each thread reads its cell's 24 u16 partials as 3 contiguous uint4 loads
// (48B, 16B-aligned: k*48 % 16 == 0) -- the wave reads 3KB contiguous.
__global__ void kout(const float* __restrict__ score, const float* __restrict__ reg,
                     const unsigned short* __restrict__ rank16,
                     const unsigned long long* __restrict__ kw,
                     float* __restrict__ out) {
    const int k = blockIdx.x * 256 + threadIdx.x;
    const uint4* rp4 = (const uint4*)(rank16 + (size_t)k * NMT);
    const uint4 p0 = rp4[0], p1 = rp4[1], p2 = rp4[2];
    const unsigned wds[12] = {p0.x, p0.y, p0.z, p0.w,
                              p1.x, p1.y, p1.z, p1.w,
                              p2.x, p2.y, p2.z, p2.w};
    unsigned r = 0;
    #pragma unroll
    for (int y = 0; y < 12; ++y) r += (wds[y] & 0xFFFFu) + (wds[y] >> 16);
    const int j = k % WW, i = k / WW;
    const bool kp = ((kw[i * 2 + (j >> 6)] >> (j & 63)) & 1ULL) != 0ULL;
    const float x1 = (float)coord1(j);
    const float y1 = (float)coord1(i);
    const float4 d = ((const float4*)reg)[k];
    float* o = out + (size_t)r * 5;
    o[0] = kp ? (x1 + d.x * 21.0f) : 0.0f;
    o[1] = kp ? (y1 + d.y * 21.0f) : 0.0f;
    o[2] = kp ? (x1 + 20.0f + d.z * 21.0f) : 0.0f;
    o[3] = kp ? (y1 + 20.0f + d.w * 21.0f) : 0.0f;
    o[4] = kp ? score[k] : 0.0f;
}

extern "C" void kernel_launch(void* const* d_in, const int* in_sizes, int n_in,
                              void* d_out, int out_size, void* d_ws, size_t ws_size,
                              hipStream_t stream) {
    const float* cls = (const float*)d_in[0];
    const float* reg = (const float*)d_in[1];
    float* out = (float*)d_out;
    char* ws = (char*)d_ws;
    unsigned short* rank16 = (unsigned short*)(ws);
    unsigned long long* kw = (unsigned long long*)(ws + KW_OFF);

    kA<<<1 + NKT * NMT, 1024, 0, stream>>>(cls, rank16, kw);
    kout<<<36, 256, 0, stream>>>(cls, reg, rank16, kw, out);
}

// Round 7
// 73.258 us; speedup vs baseline: 1.0366x; 1.0366x over previous
//
#include <hip/hip_runtime.h>
#include <stdint.h>

#define HH 96
#define WW 96
#define NN (HH*WW)
#define NW 192   // bitmap words: 96 rows x 2 (128-bit padded rows, cols 96..127 dead)
#define NMT 72   // m-tiles for rank partials
#define MT 128   // m-tile size (NMT*MT == NN)
#define NKT 3    // k-tiles of 3072 (3 keys/thread)
#define KW_OFF 2654208   // 72*9216*4

// ws layout (bytes):
//   [0, 2654208)        rankp u32[72][9216]  exact stable-rank partials
//   [2654208, 2655744)  kw    u64[192]       kept bitmap words
// R4 lesson (measured): cross-block sync via agent-scope atomics costs ~80us
// of L2-invalidate/writeback storms on multi-XCD gfx950 -> kA hit 88us.
// R6 lesson (measured): rank side is LDS-ISSUE-bound; keep per-block
// broadcast-read count at 64/thread (MT=128, NMT=72). Two dispatches with
// zero cross-block sync is the right structure (R6/R8).

__device__ __forceinline__ int coord1(int a) { return (10 * a + 1) / 3; }

// Compile-time-specialized shifted word for half H, col shift DJ.
// 128-bit row = (A low cols 0..63, B high cols 64..127); S = own-half word,
// O = other-half word. Result bit b (cell col 64H+b) = row bit (64H+b+DJ).
template<int H, int DJ>
__device__ __forceinline__ unsigned long long shf(unsigned long long S,
                                                  unsigned long long O) {
    if constexpr (DJ == 0) {
        return S;
    } else if constexpr (H == 0) {
        if constexpr (DJ > 0) return (S >> DJ) | (O << (64 - DJ));  // B feeds high bits
        else                  return (S << (-DJ));                  // left of A is 0
    } else {
        if constexpr (DJ > 0) return (S >> DJ);                     // right of B is 0
        else                  return (S << (-DJ)) | (O >> (64 + DJ)); // A feeds low bits
    }
}

// Column-geometry masks: bit b set iff cm3(col 64H+b) == 1 (C1) / == 2 (C2).
template<int H> struct CM;
template<> struct CM<0> {
    static constexpr unsigned long long C1 = 0x2492492492492492ULL;  // b%3==1
    static constexpr unsigned long long C2 = 0x4924924924924924ULL;  // b%3==2
};
template<> struct CM<1> {
    static constexpr unsigned long long C1 = 0x9249249249249249ULL;  // (b+64)%3==1
    static constexpr unsigned long long C2 = 0x2492492492492492ULL;  // (b+64)%3==2
};

// Free-running monotone fixpoint (R10 protocol preserved): one thread per
// word, h compile-time per wave. Write K-then-D, read D-then-K, volatile:
// D=1 observed => that word's K is current. Own word lives in registers.
// Derived H edges: H[+e] = ~shifted(H[-e]) & geo-mask (exact under the
// tiebreak sign convention); spurious complement bits only hit dead cells /
// padding cols (D=1,K=0 from init -> harmless), col-0 dj=-1 masked.
// Inner 3x relaxation: horizontal edges re-applied with fresh own word
// (monotone-safe with the stale-but-ordered neighbor snapshot).
template<int H>
__device__ __forceinline__ unsigned long long runfix(
    const int row, const unsigned long long* Hc,
    volatile unsigned long long* vKs, volatile unsigned long long* vKo,
    volatile unsigned long long* vDs, volatile unsigned long long* vDo,
    unsigned long long myK, unsigned long long myD) {
    const int w  = row * 2 + H;
    const int wo = row * 2 + (H ^ 1);
    const bool okm1 = row >= 1, okp1 = row <= HH - 2;
    const bool okm2 = row >= 2, okp2 = row <= HH - 3;
    const int rm3 = row % 3;
    unsigned long long Hr[12];
    {
        const unsigned long long h0s = Hc[0*NW+w], h0o = Hc[0*NW+wo];
        const unsigned long long h2s = Hc[1*NW+w], h2o = Hc[1*NW+wo];
        Hr[0] = h0s;                                  // (0,-1) computed
        Hr[1] = ~shf<H,1>(h0s, h0o);                  // (0,+1) derived
        Hr[2] = h2s;                                  // (0,-2) computed
        Hr[3] = (~shf<H,2>(h2s, h2o)) & CM<H>::C2;    // (0,+2) derived, geo cm3==2
        Hr[4] = Hc[2*NW+w];                           // (-1,0) computed
        Hr[6] = Hc[3*NW+w];                           // (-2,0) computed
        Hr[8] = Hc[4*NW+w];                           // (-1,-1) computed
        Hr[9] = Hc[5*NW+w];                           // (-1,+1) computed
        Hr[5] = okp1 ? ~Hc[2*NW+w+2] : 0ULL;          // (+1,0) derived
        Hr[7] = (okp2 && rm3 == 2) ? ~Hc[3*NW+w+4] : 0ULL;  // (+2,0) derived
        if (okp1) {
            const unsigned long long a8 = Hc[4*NW+w+2], b8 = Hc[4*NW+wo+2];
            unsigned long long t11 = ~shf<H,1>(a8, b8);    // (+1,+1) from (-1,-1)@r+1
            const unsigned long long a9 = Hc[5*NW+w+2], b9 = Hc[5*NW+wo+2];
            unsigned long long t10 = ~shf<H,-1>(a9, b9);   // (+1,-1) from (-1,+1)@r+1
            if (rm3 == 1) { t11 &= ~CM<H>::C1; t10 &= ~CM<H>::C2; }
            if constexpr (H == 0) t10 &= ~1ULL;            // col 0 has no col -1
            Hr[11] = t11; Hr[10] = t10;
        } else { Hr[11] = 0ULL; Hr[10] = 0ULL; }
    }
    for (int iter = 0; iter < 4096; ++iter) {
        if (!~myD) break;                          // fully determined: final
        // ---- D reads FIRST (out-of-grid rows: H=0 there anyway) ----
        const unsigned long long D0o  = vDo[row];
        const unsigned long long Dm1s = okm1 ? vDs[row-1] : 0ULL;
        const unsigned long long Dm1o = okm1 ? vDo[row-1] : 0ULL;
        const unsigned long long Dp1s = okp1 ? vDs[row+1] : 0ULL;
        const unsigned long long Dp1o = okp1 ? vDo[row+1] : 0ULL;
        const unsigned long long Dm2  = okm2 ? vDs[row-2] : 0ULL;
        const unsigned long long Dp2  = okp2 ? vDs[row+2] : 0ULL;
        // ---- K reads AFTER D ----
        const unsigned long long K0o  = vKo[row];
        const unsigned long long Km1s = okm1 ? vKs[row-1] : 0ULL;
        const unsigned long long Km1o = okm1 ? vKo[row-1] : 0ULL;
        const unsigned long long Kp1s = okp1 ? vKs[row+1] : 0ULL;
        const unsigned long long Kp1o = okp1 ? vKo[row+1] : 0ULL;
        const unsigned long long Km2  = okm2 ? vKs[row-2] : 0ULL;
        const unsigned long long Kp2  = okp2 ? vKs[row+2] : 0ULL;

        const unsigned long long suppV =
              (Hr[4]  & Km1s) | (Hr[5] & Kp1s) | (Hr[6] & Km2) | (Hr[7] & Kp2)
            | (Hr[8]  & shf<H,-1>(Km1s, Km1o)) | (Hr[9]  & shf<H,1>(Km1s, Km1o))
            | (Hr[10] & shf<H,-1>(Kp1s, Kp1o)) | (Hr[11] & shf<H,1>(Kp1s, Kp1o));
        unsigned long long alldetV = ~0ULL;
        alldetV &= ~Hr[4]  | Dm1s;
        alldetV &= ~Hr[5]  | Dp1s;
        alldetV &= ~Hr[6]  | Dm2;
        alldetV &= ~Hr[7]  | Dp2;
        alldetV &= ~Hr[8]  | shf<H,-1>(Dm1s, Dm1o);
        alldetV &= ~Hr[9]  | shf<H,1>(Dm1s, Dm1o);
        alldetV &= ~Hr[10] | shf<H,-1>(Dp1s, Dp1o);
        alldetV &= ~Hr[11] | shf<H,1>(Dp1s, Dp1o);

        #pragma unroll
        for (int in = 0; in < 3; ++in) {           // horizontal in-register relax
            const unsigned long long supp = suppV
                | (Hr[0] & shf<H,-1>(myK, K0o)) | (Hr[1] & shf<H,1>(myK, K0o))
                | (Hr[2] & shf<H,-2>(myK, K0o)) | (Hr[3] & shf<H,2>(myK, K0o));
            const unsigned long long alldet = alldetV
                & (~Hr[0] | shf<H,-1>(myD, D0o)) & (~Hr[1] | shf<H,1>(myD, D0o))
                & (~Hr[2] | shf<H,-2>(myD, D0o)) & (~Hr[3] | shf<H,2>(myD, D0o));
            const unsigned long long U = ~myD;
            myK |= U & alldet & ~supp;
            myD |= U & (supp | alldet);
        }
        vKs[row] = myK;                            // K write BEFORE D write
        vDs[row] = myD;
    }
    return myK;
}

// One dispatch, disjoint block roles, ZERO cross-block sync (R6/R8 + R4).
// Block 0: bit-parallel greedy NMS. Blocks 1..216: exact stable-rank
// partials via u64 packed keys, 3 k-keys per thread amortize each LDS
// broadcast read over 6 compares (64 broadcast reads/thread -- R6 lesson).
//   key = (score_bits<<14) | (16383-idx):  key_m > key_k  <=>
//   (b_m > b_k) || (b_m==b_k && m<k)  -- single 64-bit compare per element.
__global__ __launch_bounds__(1024, 1) void kA(const float* __restrict__ cls,
                                              unsigned int* __restrict__ rankp,
                                              unsigned long long* __restrict__ kw) {
    __shared__ __align__(16) float s[NN];         // 36 KB (rank blocks alias 1 KB)
    __shared__ unsigned long long Hc[6][NW];      // 9 KB (computed-edge masks)
    __shared__ unsigned long long K2[2][HH], D2[2][HH];   // [h][row], 3 KB
    const int tid = threadIdx.x;
    const int bid = blockIdx.x;

    if (bid != 0) {
        // ---- rank partials: (k-tile of 3072, 3 keys/thread) x (m-tile of 128) ----
        const int rb = bid - 1;
        const int kt = rb % NKT, mt = rb / NKT;
        const int base = mt * MT;
        unsigned long long* sk = (unsigned long long*)s;
        if (tid < MT) {
            const int m = base + tid;
            sk[tid] = ((unsigned long long)__float_as_uint(cls[m]) << 14)
                    | (unsigned long long)(16383 - m);
        }
        __syncthreads();
        const int k0 = kt * 3072 + tid;
        const unsigned long long kk0 =
            ((unsigned long long)__float_as_uint(cls[k0]) << 14)
          | (unsigned long long)(16383 - k0);
        const unsigned long long kk1 =
            ((unsigned long long)__float_as_uint(cls[k0 + 1024]) << 14)
          | (unsigned long long)(16383 - (k0 + 1024));
        const unsigned long long kk2 =
            ((unsigned long long)__float_as_uint(cls[k0 + 2048]) << 14)
          | (unsigned long long)(16383 - (k0 + 2048));
        const ulonglong2* sk2 = (const ulonglong2*)sk;
        unsigned a0 = 0, a1 = 0, a2 = 0;
        #pragma unroll 8
        for (int m2 = 0; m2 < MT / 2; ++m2) {
            const ulonglong2 v = sk2[m2];   // broadcast read, conflict-free
            a0 += (v.x > kk0) + (v.y > kk0);
            a1 += (v.x > kk1) + (v.y > kk1);
            a2 += (v.x > kk2) + (v.y > kk2);
        }
        unsigned int* rp = rankp + mt * NN + k0;
        rp[0] = a0; rp[1024] = a1; rp[2048] = a2;
        return;
    }

    // ---- NMS block (bid == 0) ----
    const int lane = tid & 63;
    const int wave = __builtin_amdgcn_readfirstlane(tid >> 6);  // force SALU
    for (int i = tid; i < NN/4; i += 1024)
        ((float4*)s)[i] = ((const float4*)cls)[i];
    __syncthreads();
    // Build 6 computed H masks (all tb: >=) + K/D init via ballot. Geometry
    // and bounds are folded into per-word CONSTANT masks applied to the
    // ballot result (scalar ops; wave/row/h forced wave-uniform), so the
    // per-lane work is just clamp+read+compare. Clamped OOB neighbor reads
    // stay inside s[] (garbage value, masked out). Mask content verified
    // edge-by-edge identical to the predicate form (col>=2 for (0,-2) via
    // ~3; col<=94 for (-1,+1) via bit31; dead cols via I; rows via 0-word).
    for (int it = 0; it < 12; ++it) {
        const int w = wave + (it << 4);
        const int row = w >> 1;
        const int h = w & 1;
        const int col = (h << 6) + lane;
        const int c = row * WW + col;
        const int cc = c < NN ? c : NN - 1;
        const unsigned bc = __float_as_uint(s[cc]);
        const int rm3 = row % 3;
        const unsigned long long I  = h ? 0x00000000FFFFFFFFULL : ~0ULL;
        const unsigned long long C1 = h ? 0x9249249249249249ULL : 0x2492492492492492ULL;
        const unsigned long long C2 = h ? 0x2492492492492492ULL : 0x4924924924924924ULL;
        const unsigned long long dinit = __ballot(!(__uint_as_float(bc) > 0.6f)) | ~I;
        if (lane == 0) { D2[h][row] = dinit; K2[h][row] = 0ULL; }
        auto nb = [&](int off) -> unsigned long long {
            int v = c + off;
            v = v < 0 ? 0 : (v >= NN ? NN - 1 : v);
            return __ballot(__float_as_uint(s[v]) >= bc);
        };
        const unsigned long long b0 = nb(-1);        // (0,-1)
        const unsigned long long b1 = nb(-2);        // (0,-2)
        const unsigned long long b2 = nb(-WW);       // (-1,0)
        const unsigned long long b3 = nb(-2*WW);     // (-2,0)
        const unsigned long long b4 = nb(-WW-1);     // (-1,-1)
        const unsigned long long b5 = nb(-WW+1);     // (-1,+1)
        if (lane == 0) {
            Hc[0][w] = b0 & I & (h ? ~0ULL : ~1ULL);
            Hc[1][w] = b1 & I & C1 & (h ? ~0ULL : ~3ULL);
            Hc[2][w] = (row >= 1) ? (b2 & I) : 0ULL;
            Hc[3][w] = (row >= 2 && rm3 == 1) ? (b3 & I) : 0ULL;
            Hc[4][w] = (row >= 1)
                ? (b4 & I & (rm3 == 2 ? ~C2 : ~0ULL) & (h ? ~0ULL : ~1ULL)) : 0ULL;
            Hc[5][w] = (row >= 1)
                ? (b5 & I & (rm3 == 2 ? ~C1 : ~0ULL)
                      & (h ? 0xFFFFFFFF7FFFFFFFULL : ~0ULL)) : 0ULL;
        }
    }
    __syncthreads();          // last barrier: all 16 waves present
    // Fixpoint threads: 4 waves x 48 lanes; h = wave>>1 is WAVE-UNIFORM so
    // the loop is compile-time specialized by half (no runtime h selects).
    if (wave >= 4 || lane >= 48) return;
    const int h2 = wave >> 1;
    const int row = ((wave & 1) * 48) + lane;
    const unsigned long long myK = K2[h2][row], myD = D2[h2][row];
    unsigned long long fin;
    if (h2 == 0)
        fin = runfix<0>(row, &Hc[0][0],
                        (volatile unsigned long long*)&K2[0][0],
                        (volatile unsigned long long*)&K2[1][0],
                        (volatile unsigned long long*)&D2[0][0],
                        (volatile unsigned long long*)&D2[1][0], myK, myD);
    else
        fin = runfix<1>(row, &Hc[0][0],
                        (volatile unsigned long long*)&K2[1][0],
                        (volatile unsigned long long*)&K2[0][0],
                        (volatile unsigned long long*)&D2[1][0],
                        (volatile unsigned long long*)&D2[0][0], myK, myD);
    kw[row * 2 + h2] = fin;   // own word final; no cross-wave read needed
}

// Epilogue: r = rank[k] is a permutation of [0,9216) — every output row
// written exactly once (non-kept rows -> zeros, no d_out memset needed).
// 8 lanes per cell: each lane sums 9 of the 72 partials, 3-step shfl_xor
// reduce within the 8-lane group (in-wave, groups 8-aligned), lane s==0
// writes. 72 blocks -> 72 CUs; load chain per thread 72 -> 9.
__global__ void kout(const float* __restrict__ score, const float* __restrict__ reg,
                     const unsigned int* __restrict__ rankp,
                     const unsigned long long* __restrict__ kw,
                     float* __restrict__ out) {
    const int g = blockIdx.x * 1024 + threadIdx.x;   // 72*1024 = 9216*8
    const int k = g >> 3, ssub = g & 7;
    unsigned r = 0;
    #pragma unroll
    for (int q = 0; q < 9; ++q) r += rankp[(ssub * 9 + q) * NN + k];
    r += __shfl_xor(r, 1);
    r += __shfl_xor(r, 2);
    r += __shfl_xor(r, 4);
    if (ssub == 0) {
        const int j = k % WW, i = k / WW;
        const bool kp = ((kw[i * 2 + (j >> 6)] >> (j & 63)) & 1ULL) != 0ULL;
        const float x1 = (float)coord1(j);
        const float y1 = (float)coord1(i);
        const float4 d = ((const float4*)reg)[k];
        float* o = out + (size_t)r * 5;
        o[0] = kp ? (x1 + d.x * 21.0f) : 0.0f;
        o[1] = kp ? (y1 + d.y * 21.0f) : 0.0f;
        o[2] = kp ? (x1 + 20.0f + d.z * 21.0f) : 0.0f;
        o[3] = kp ? (y1 + 20.0f + d.w * 21.0f) : 0.0f;
        o[4] = kp ? score[k] : 0.0f;
    }
}

extern "C" void kernel_launch(void* const* d_in, const int* in_sizes, int n_in,
                              void* d_out, int out_size, void* d_ws, size_t ws_size,
                              hipStream_t stream) {
    const float* cls = (const float*)d_in[0];
    const float* reg = (const float*)d_in[1];
    float* out = (float*)d_out;
    char* ws = (char*)d_ws;
    unsigned int* rankp = (unsigned int*)(ws);
    unsigned long long* kw = (unsigned long long*)(ws + KW_OFF);

    kA<<<1 + NKT * NMT, 1024, 0, stream>>>(cls, rankp, kw);
    kout<<<72, 1024, 0, stream>>>(cls, reg, rankp, kw, out);
}

// Round 8
// 72.187 us; speedup vs baseline: 1.0520x; 1.0148x over previous
//
#include <hip/hip_runtime.h>
#include <stdint.h>

#define HH 96
#define WW 96
#define NN (HH*WW)
#define NW 192   // bitmap words: 96 rows x 2 (128-bit padded rows, cols 96..127 dead)
#define NMT 72   // m-tiles for rank partials
#define MT 128   // m-tile size (NMT*MT == NN)
#define NKT 3    // k-tiles of 3072 (3 keys/thread)
#define KW_OFF 2654208   // 72*9216*4

// ws layout (bytes):
//   [0, 2654208)        rankp u32[72][9216]  exact stable-rank partials
//   [2654208, 2655744)  kw    u64[192]       kept bitmap words
// R4 lesson (measured): cross-block sync via agent-scope atomics costs ~80us
// of L2-invalidate/writeback storms on multi-XCD gfx950 -> kA hit 88us.
// R6 lesson (measured): rank side is LDS-ISSUE-bound; keep per-block
// broadcast-read count at 64/thread (MT=128, NMT=72).
// R7 lesson (measured): widening kout parallelism is neutral (load count
// unchanged); 36x256 scalar-sum kout is at the launch floor.
// This is the best harness-verified configuration (R5: 72.19us).

__device__ __forceinline__ int coord1(int a) { return (10 * a + 1) / 3; }

// Compile-time-specialized shifted word for half H, col shift DJ.
// 128-bit row = (A low cols 0..63, B high cols 64..127); S = own-half word,
// O = other-half word. Result bit b (cell col 64H+b) = row bit (64H+b+DJ).
template<int H, int DJ>
__device__ __forceinline__ unsigned long long shf(unsigned long long S,
                                                  unsigned long long O) {
    if constexpr (DJ == 0) {
        return S;
    } else if constexpr (H == 0) {
        if constexpr (DJ > 0) return (S >> DJ) | (O << (64 - DJ));  // B feeds high bits
        else                  return (S << (-DJ));                  // left of A is 0
    } else {
        if constexpr (DJ > 0) return (S >> DJ);                     // right of B is 0
        else                  return (S << (-DJ)) | (O >> (64 + DJ)); // A feeds low bits
    }
}

// Column-geometry masks: bit b set iff cm3(col 64H+b) == 1 (C1) / == 2 (C2).
template<int H> struct CM;
template<> struct CM<0> {
    static constexpr unsigned long long C1 = 0x2492492492492492ULL;  // b%3==1
    static constexpr unsigned long long C2 = 0x4924924924924924ULL;  // b%3==2
};
template<> struct CM<1> {
    static constexpr unsigned long long C1 = 0x9249249249249249ULL;  // (b+64)%3==1
    static constexpr unsigned long long C2 = 0x2492492492492492ULL;  // (b+64)%3==2
};

// Free-running monotone fixpoint (R10 protocol preserved): one thread per
// word, h compile-time per wave. Write K-then-D, read D-then-K, volatile:
// D=1 observed => that word's K is current. Own word lives in registers.
// Derived H edges: H[+e] = ~shifted(H[-e]) & geo-mask (exact under the
// tiebreak sign convention); spurious complement bits only hit dead cells /
// padding cols (D=1,K=0 from init -> harmless), col-0 dj=-1 masked.
// Inner 3x relaxation: horizontal edges re-applied with fresh own word
// (monotone-safe with the stale-but-ordered neighbor snapshot).
template<int H>
__device__ __forceinline__ unsigned long long runfix(
    const int row, const unsigned long long* Hc,
    volatile unsigned long long* vKs, volatile unsigned long long* vKo,
    volatile unsigned long long* vDs, volatile unsigned long long* vDo,
    unsigned long long myK, unsigned long long myD) {
    const int w  = row * 2 + H;
    const int wo = row * 2 + (H ^ 1);
    const bool okm1 = row >= 1, okp1 = row <= HH - 2;
    const bool okm2 = row >= 2, okp2 = row <= HH - 3;
    const int rm3 = row % 3;
    unsigned long long Hr[12];
    {
        const unsigned long long h0s = Hc[0*NW+w], h0o = Hc[0*NW+wo];
        const unsigned long long h2s = Hc[1*NW+w], h2o = Hc[1*NW+wo];
        Hr[0] = h0s;                                  // (0,-1) computed
        Hr[1] = ~shf<H,1>(h0s, h0o);                  // (0,+1) derived
        Hr[2] = h2s;                                  // (0,-2) computed
        Hr[3] = (~shf<H,2>(h2s, h2o)) & CM<H>::C2;    // (0,+2) derived, geo cm3==2
        Hr[4] = Hc[2*NW+w];                           // (-1,0) computed
        Hr[6] = Hc[3*NW+w];                           // (-2,0) computed
        Hr[8] = Hc[4*NW+w];                           // (-1,-1) computed
        Hr[9] = Hc[5*NW+w];                           // (-1,+1) computed
        Hr[5] = okp1 ? ~Hc[2*NW+w+2] : 0ULL;          // (+1,0) derived
        Hr[7] = (okp2 && rm3 == 2) ? ~Hc[3*NW+w+4] : 0ULL;  // (+2,0) derived
        if (okp1) {
            const unsigned long long a8 = Hc[4*NW+w+2], b8 = Hc[4*NW+wo+2];
            unsigned long long t11 = ~shf<H,1>(a8, b8);    // (+1,+1) from (-1,-1)@r+1
            const unsigned long long a9 = Hc[5*NW+w+2], b9 = Hc[5*NW+wo+2];
            unsigned long long t10 = ~shf<H,-1>(a9, b9);   // (+1,-1) from (-1,+1)@r+1
            if (rm3 == 1) { t11 &= ~CM<H>::C1; t10 &= ~CM<H>::C2; }
            if constexpr (H == 0) t10 &= ~1ULL;            // col 0 has no col -1
            Hr[11] = t11; Hr[10] = t10;
        } else { Hr[11] = 0ULL; Hr[10] = 0ULL; }
    }
    for (int iter = 0; iter < 4096; ++iter) {
        if (!~myD) break;                          // fully determined: final
        // ---- D reads FIRST (out-of-grid rows: H=0 there anyway) ----
        const unsigned long long D0o  = vDo[row];
        const unsigned long long Dm1s = okm1 ? vDs[row-1] : 0ULL;
        const unsigned long long Dm1o = okm1 ? vDo[row-1] : 0ULL;
        const unsigned long long Dp1s = okp1 ? vDs[row+1] : 0ULL;
        const unsigned long long Dp1o = okp1 ? vDo[row+1] : 0ULL;
        const unsigned long long Dm2  = okm2 ? vDs[row-2] : 0ULL;
        const unsigned long long Dp2  = okp2 ? vDs[row+2] : 0ULL;
        // ---- K reads AFTER D ----
        const unsigned long long K0o  = vKo[row];
        const unsigned long long Km1s = okm1 ? vKs[row-1] : 0ULL;
        const unsigned long long Km1o = okm1 ? vKo[row-1] : 0ULL;
        const unsigned long long Kp1s = okp1 ? vKs[row+1] : 0ULL;
        const unsigned long long Kp1o = okp1 ? vKo[row+1] : 0ULL;
        const unsigned long long Km2  = okm2 ? vKs[row-2] : 0ULL;
        const unsigned long long Kp2  = okp2 ? vKs[row+2] : 0ULL;

        const unsigned long long suppV =
              (Hr[4]  & Km1s) | (Hr[5] & Kp1s) | (Hr[6] & Km2) | (Hr[7] & Kp2)
            | (Hr[8]  & shf<H,-1>(Km1s, Km1o)) | (Hr[9]  & shf<H,1>(Km1s, Km1o))
            | (Hr[10] & shf<H,-1>(Kp1s, Kp1o)) | (Hr[11] & shf<H,1>(Kp1s, Kp1o));
        unsigned long long alldetV = ~0ULL;
        alldetV &= ~Hr[4]  | Dm1s;
        alldetV &= ~Hr[5]  | Dp1s;
        alldetV &= ~Hr[6]  | Dm2;
        alldetV &= ~Hr[7]  | Dp2;
        alldetV &= ~Hr[8]  | shf<H,-1>(Dm1s, Dm1o);
        alldetV &= ~Hr[9]  | shf<H,1>(Dm1s, Dm1o);
        alldetV &= ~Hr[10] | shf<H,-1>(Dp1s, Dp1o);
        alldetV &= ~Hr[11] | shf<H,1>(Dp1s, Dp1o);

        #pragma unroll
        for (int in = 0; in < 3; ++in) {           // horizontal in-register relax
            const unsigned long long supp = suppV
                | (Hr[0] & shf<H,-1>(myK, K0o)) | (Hr[1] & shf<H,1>(myK, K0o))
                | (Hr[2] & shf<H,-2>(myK, K0o)) | (Hr[3] & shf<H,2>(myK, K0o));
            const unsigned long long alldet = alldetV
                & (~Hr[0] | shf<H,-1>(myD, D0o)) & (~Hr[1] | shf<H,1>(myD, D0o))
                & (~Hr[2] | shf<H,-2>(myD, D0o)) & (~Hr[3] | shf<H,2>(myD, D0o));
            const unsigned long long U = ~myD;
            myK |= U & alldet & ~supp;
            myD |= U & (supp | alldet);
        }
        vKs[row] = myK;                            // K write BEFORE D write
        vDs[row] = myD;
    }
    return myK;
}

// One dispatch, disjoint block roles, ZERO cross-block sync (R6/R8 + R4).
// Block 0: bit-parallel greedy NMS. Blocks 1..216: exact stable-rank
// partials via u64 packed keys, 3 k-keys per thread amortize each LDS
// broadcast read over 6 compares (64 broadcast reads/thread -- R6 lesson).
//   key = (score_bits<<14) | (16383-idx):  key_m > key_k  <=>
//   (b_m > b_k) || (b_m==b_k && m<k)  -- single 64-bit compare per element.
__global__ __launch_bounds__(1024, 1) void kA(const float* __restrict__ cls,
                                              unsigned int* __restrict__ rankp,
                                              unsigned long long* __restrict__ kw) {
    __shared__ __align__(16) float s[NN];         // 36 KB (rank blocks alias 1 KB)
    __shared__ unsigned long long Hc[6][NW];      // 9 KB (computed-edge masks)
    __shared__ unsigned long long K2[2][HH], D2[2][HH];   // [h][row], 3 KB
    const int tid = threadIdx.x;
    const int bid = blockIdx.x;

    if (bid != 0) {
        // ---- rank partials: (k-tile of 3072, 3 keys/thread) x (m-tile of 128) ----
        const int rb = bid - 1;
        const int kt = rb % NKT, mt = rb / NKT;
        const int base = mt * MT;
        unsigned long long* sk = (unsigned long long*)s;
        if (tid < MT) {
            const int m = base + tid;
            sk[tid] = ((unsigned long long)__float_as_uint(cls[m]) << 14)
                    | (unsigned long long)(16383 - m);
        }
        __syncthreads();
        const int k0 = kt * 3072 + tid;
        const unsigned long long kk0 =
            ((unsigned long long)__float_as_uint(cls[k0]) << 14)
          | (unsigned long long)(16383 - k0);
        const unsigned long long kk1 =
            ((unsigned long long)__float_as_uint(cls[k0 + 1024]) << 14)
          | (unsigned long long)(16383 - (k0 + 1024));
        const unsigned long long kk2 =
            ((unsigned long long)__float_as_uint(cls[k0 + 2048]) << 14)
          | (unsigned long long)(16383 - (k0 + 2048));
        const ulonglong2* sk2 = (const ulonglong2*)sk;
        unsigned a0 = 0, a1 = 0, a2 = 0;
        #pragma unroll 8
        for (int m2 = 0; m2 < MT / 2; ++m2) {
            const ulonglong2 v = sk2[m2];   // broadcast read, conflict-free
            a0 += (v.x > kk0) + (v.y > kk0);
            a1 += (v.x > kk1) + (v.y > kk1);
            a2 += (v.x > kk2) + (v.y > kk2);
        }
        unsigned int* rp = rankp + mt * NN + k0;
        rp[0] = a0; rp[1024] = a1; rp[2048] = a2;
        return;
    }

    // ---- NMS block (bid == 0) ----
    const int lane = tid & 63;
    const int wave = __builtin_amdgcn_readfirstlane(tid >> 6);  // force SALU
    for (int i = tid; i < NN/4; i += 1024)
        ((float4*)s)[i] = ((const float4*)cls)[i];
    __syncthreads();
    // Build 6 computed H masks (all tb: >=) + K/D init via ballot. Geometry
    // and bounds are folded into per-word CONSTANT masks applied to the
    // ballot result (scalar ops; wave/row/h forced wave-uniform), so the
    // per-lane work is just clamp+read+compare. Clamped OOB neighbor reads
    // stay inside s[] (garbage value, masked out). Mask content verified
    // edge-by-edge identical to the predicate form (col>=2 for (0,-2) via
    // ~3; col<=94 for (-1,+1) via bit31; dead cols via I; rows via 0-word).
    for (int it = 0; it < 12; ++it) {
        const int w = wave + (it << 4);
        const int row = w >> 1;
        const int h = w & 1;
        const int col = (h << 6) + lane;
        const int c = row * WW + col;
        const int cc = c < NN ? c : NN - 1;
        const unsigned bc = __float_as_uint(s[cc]);
        const int rm3 = row % 3;
        const unsigned long long I  = h ? 0x00000000FFFFFFFFULL : ~0ULL;
        const unsigned long long C1 = h ? 0x9249249249249249ULL : 0x2492492492492492ULL;
        const unsigned long long C2 = h ? 0x2492492492492492ULL : 0x4924924924924924ULL;
        const unsigned long long dinit = __ballot(!(__uint_as_float(bc) > 0.6f)) | ~I;
        if (lane == 0) { D2[h][row] = dinit; K2[h][row] = 0ULL; }
        auto nb = [&](int off) -> unsigned long long {
            int v = c + off;
            v = v < 0 ? 0 : (v >= NN ? NN - 1 : v);
            return __ballot(__float_as_uint(s[v]) >= bc);
        };
        const unsigned long long b0 = nb(-1);        // (0,-1)
        const unsigned long long b1 = nb(-2);        // (0,-2)
        const unsigned long long b2 = nb(-WW);       // (-1,0)
        const unsigned long long b3 = nb(-2*WW);     // (-2,0)
        const unsigned long long b4 = nb(-WW-1);     // (-1,-1)
        const unsigned long long b5 = nb(-WW+1);     // (-1,+1)
        if (lane == 0) {
            Hc[0][w] = b0 & I & (h ? ~0ULL : ~1ULL);
            Hc[1][w] = b1 & I & C1 & (h ? ~0ULL : ~3ULL);
            Hc[2][w] = (row >= 1) ? (b2 & I) : 0ULL;
            Hc[3][w] = (row >= 2 && rm3 == 1) ? (b3 & I) : 0ULL;
            Hc[4][w] = (row >= 1)
                ? (b4 & I & (rm3 == 2 ? ~C2 : ~0ULL) & (h ? ~0ULL : ~1ULL)) : 0ULL;
            Hc[5][w] = (row >= 1)
                ? (b5 & I & (rm3 == 2 ? ~C1 : ~0ULL)
                      & (h ? 0xFFFFFFFF7FFFFFFFULL : ~0ULL)) : 0ULL;
        }
    }
    __syncthreads();          // last barrier: all 16 waves present
    // Fixpoint threads: 4 waves x 48 lanes; h = wave>>1 is WAVE-UNIFORM so
    // the loop is compile-time specialized by half (no runtime h selects).
    if (wave >= 4 || lane >= 48) return;
    const int h2 = wave >> 1;
    const int row = ((wave & 1) * 48) + lane;
    const unsigned long long myK = K2[h2][row], myD = D2[h2][row];
    unsigned long long fin;
    if (h2 == 0)
        fin = runfix<0>(row, &Hc[0][0],
                        (volatile unsigned long long*)&K2[0][0],
                        (volatile unsigned long long*)&K2[1][0],
                        (volatile unsigned long long*)&D2[0][0],
                        (volatile unsigned long long*)&D2[1][0], myK, myD);
    else
        fin = runfix<1>(row, &Hc[0][0],
                        (volatile unsigned long long*)&K2[1][0],
                        (volatile unsigned long long*)&K2[0][0],
                        (volatile unsigned long long*)&D2[1][0],
                        (volatile unsigned long long*)&D2[0][0], myK, myD);
    kw[row * 2 + h2] = fin;   // own word final; no cross-wave read needed
}

// Epilogue: r = rank[k] is a permutation of [0,9216) — every output row
// written exactly once (non-kept rows -> zeros, no d_out memset needed).
__global__ void kout(const float* __restrict__ score, const float* __restrict__ reg,
                     const unsigned int* __restrict__ rankp,
                     const unsigned long long* __restrict__ kw,
                     float* __restrict__ out) {
    const int k = blockIdx.x * 256 + threadIdx.x;
    unsigned r = 0;
    #pragma unroll
    for (int y = 0; y < NMT; ++y) r += rankp[y * NN + k];
    const int j = k % WW, i = k / WW;
    const bool kp = ((kw[i * 2 + (j >> 6)] >> (j & 63)) & 1ULL) != 0ULL;
    const float x1 = (float)coord1(j);
    const float y1 = (float)coord1(i);
    const float4 d = ((const float4*)reg)[k];
    float* o = out + (size_t)r * 5;
    o[0] = kp ? (x1 + d.x * 21.0f) : 0.0f;
    o[1] = kp ? (y1 + d.y * 21.0f) : 0.0f;
    o[2] = kp ? (x1 + 20.0f + d.z * 21.0f) : 0.0f;
    o[3] = kp ? (y1 + 20.0f + d.w * 21.0f) : 0.0f;
    o[4] = kp ? score[k] : 0.0f;
}

extern "C" void kernel_launch(void* const* d_in, const int* in_sizes, int n_in,
                              void* d_out, int out_size, void* d_ws, size_t ws_size,
                              hipStream_t stream) {
    const float* cls = (const float*)d_in[0];
    const float* reg = (const float*)d_in[1];
    float* out = (float*)d_out;
    char* ws = (char*)d_ws;
    unsigned int* rankp = (unsigned int*)(ws);
    unsigned long long* kw = (unsigned long long*)(ws + KW_OFF);

    kA<<<1 + NKT * NMT, 1024, 0, stream>>>(cls, rankp, kw);
    kout<<<36, 256, 0, stream>>>(cls, reg, rankp, kw, out);
}